// Round 10
// baseline (401.432 us; speedup 1.0000x reference)
//
#include <hip/hip_runtime.h>

#define TOPK    32
#define ROW     32768
#define THREADS 512
#define WAVES   8
#define VPT     16     // float4 per thread: 16 * 4 * 512 = 32768
#define BINS    2048
#define CAP     1024
#define NBLK    512    // 2 persistent blocks per CU
#define DELAY_ITERS 3600   // ~7us dependent-FMA spin (4cyc/iter @ ~2.1GHz)

typedef unsigned int u32;

__device__ __forceinline__ u32 f2key(float f) {
    // monotone bijection: larger float -> larger uint
    u32 u = __float_as_uint(f);
    return u ^ (0x80000000u | (u32)((int)u >> 31));
}
__device__ __forceinline__ float key2f(u32 k) {
    u32 u = (k & 0x80000000u) ? (k & 0x7fffffffu) : ~k;
    return __uint_as_float(u);
}

// LDS-only barrier: orders LDS ops across the block WITHOUT draining vmcnt,
// so this row's stores / loads keep flowing under the select phase.
__device__ __forceinline__ void bar_lds() {
    asm volatile("s_waitcnt lgkmcnt(0)" ::: "memory");
    __builtin_amdgcn_s_barrier();
}

struct Shared {
    u32 hist[BINS];
    u32 wsum[WAVES];
    u32 sel_g, sel_gabove;
    u32 sel_bin, sel_above;
    u32 cand_cnt;
    u32 cnt_s;
    float Tf;
    u32 idxcut;
    u32 delay;
    float ckey[CAP];
    u32 cidx[CAP];
};

// Find bin B = max index with sum_{b>=B} hist[b] >= kk.
// Writes sh.sel_bin (=B) and sh.sel_above (= count in bins > B).
// Requires total >= kk. Ends with bar_lds().
__device__ __forceinline__ void hist_select(Shared& sh, int t, int lane,
                                            int wave, u32 kk) {
    const int base = wave * 256 + lane * 4;
    u32 h0 = sh.hist[base + 0], h1 = sh.hist[base + 1];
    u32 h2 = sh.hist[base + 2], h3 = sh.hist[base + 3];
    u32 p = h0 + h1 + h2 + h3;
    u32 s = p;  // suffix-inclusive sum over lanes >= lane
#pragma unroll
    for (int off = 1; off < 64; off <<= 1) {
        u32 vv = __shfl_down(s, off);
        if (lane + off < 64) s += vv;
    }
    if (lane == 0) sh.wsum[wave] = s;
    bar_lds();

    if (t == 0) {
        u32 above = 0; int g = WAVES - 1;
        for (int w = WAVES - 1; w >= 0; --w) {
            if (above + sh.wsum[w] >= kk) { g = w; break; }
            above += sh.wsum[w];
        }
        sh.sel_g = (u32)g; sh.sel_gabove = above;
    }
    bar_lds();

    if (wave == (int)sh.sel_g) {
        u32 a = sh.sel_gabove + (s - p);
        u32 hh[4] = {h0, h1, h2, h3};
#pragma unroll
        for (int j = 3; j >= 0; --j) {
            u32 h = hh[j];
            if (a < kk && a + h >= kk) {
                sh.sel_bin = (u32)(base + j);
                sh.sel_above = a;
            }
            a += h;
        }
    }
    bar_lds();
}

__device__ __forceinline__ void process_row(Shared& sh,
                                            const float* __restrict__ xrow,
                                            float* __restrict__ orow,
                                            int t, int lane, int wave) {
    const float4* __restrict__ xin  = (const float4*)xrow;
    float4*       __restrict__ xout = (float4*)orow;

    // load row into registers (coalesced)
    float4 v[VPT];
#pragma unroll
    for (int i = 0; i < VPT; ++i) v[i] = xin[i * THREADS + t];

    // zero hist + counters (plain LDS writes; ordered by bar_lds below)
#pragma unroll
    for (int b = 0; b < BINS / THREADS; ++b) sh.hist[t + b * THREADS] = 0;
    if (t == 0) sh.cand_cnt = 0;

    // per-thread max: compiler interleaves the fmax chain with load drain
    float m = -__builtin_inff();
#pragma unroll
    for (int i = 0; i < VPT; ++i)
        m = fmaxf(m, fmaxf(fmaxf(v[i].x, v[i].y), fmaxf(v[i].z, v[i].w)));

    bar_lds();
    atomicAdd(&sh.hist[f2key(m) >> 21], 1u);   // 512 maxima -> 2048 bins
    bar_lds();

    hist_select(sh, t, lane, wave, TOPK);

    // L = lower edge of crossing bin. The top-32 thread-maxima are 32
    // distinct elements >= L => true 32nd-largest >= L => {x >= L} holds
    // the full top-32 (and C >= 32).
    const float L = key2f(sh.sel_bin << 21);

    // gather candidates
#pragma unroll
    for (int i = 0; i < VPT; ++i) {
#pragma unroll
        for (int j = 0; j < 4; ++j) {
            float f = (&v[i].x)[j];
            if (f >= L) {
                u32 pos = atomicAdd(&sh.cand_cnt, 1u);
                if (pos < CAP) {
                    sh.ckey[pos] = f;
                    sh.cidx[pos] = (u32)((i * THREADS + t) * 4 + j);
                }
            }
        }
    }
    bar_lds();
    const u32 C = sh.cand_cnt;

    if (C <= CAP) {
        // exact rank-(TOPK-1) among candidates: order = (value desc, idx asc)
        for (u32 i = t; i < C; i += THREADS) {
            float ki = sh.ckey[i]; u32 ii = sh.cidx[i];
            u32 r = 0;
            for (u32 j = 0; j < C; ++j) {
                float kj = sh.ckey[j];
                u32 ij = sh.cidx[j];
                r += (kj > ki || (kj == ki && ij < ii)) ? 1u : 0u;
            }
            if (r == TOPK - 1) { sh.Tf = ki; sh.idxcut = ii; }
        }
        bar_lds();
        const float T = sh.Tf;
        const u32 ic = sh.idxcut;
#pragma unroll
        for (int i = 0; i < VPT; ++i) {
            float4 o;
#pragma unroll
            for (int j = 0; j < 4; ++j) {
                float f = (&v[i].x)[j];
                u32 idx = (u32)((i * THREADS + t) * 4 + j);
                (&o.x)[j] = (f > T || (f == T && idx <= ic)) ? f : 0.0f;
            }
            xout[i * THREADS + t] = o;
        }
        return;
    }

    // ---- fallback (C > CAP, adversarial data): exact radix select ----
    u32 prefix = 0; int pbits = 0;
    u32 kk = TOPK, e = 0;
    for (int r = 0; r < 3; ++r) {
        const int shift = (r == 0) ? 21 : (r == 1 ? 10 : 0);
        const int bits  = (r == 2) ? 10 : 11;
        const u32 msk = (1u << bits) - 1u;
        bar_lds();  // protect prior hist reads before re-zeroing
#pragma unroll
        for (int b = 0; b < BINS / THREADS; ++b) sh.hist[t + b * THREADS] = 0;
        bar_lds();
#pragma unroll
        for (int i = 0; i < VPT; ++i) {
#pragma unroll
            for (int j = 0; j < 4; ++j) {
                u32 key = f2key((&v[i].x)[j]);
                bool match = (pbits == 0) || ((key >> (32 - pbits)) == prefix);
                if (match) atomicAdd(&sh.hist[(key >> shift) & msk], 1u);
            }
        }
        bar_lds();
        hist_select(sh, t, lane, wave, kk);
        kk = kk - sh.sel_above;
        e  = sh.hist[sh.sel_bin];
        prefix = (prefix << bits) | sh.sel_bin;
        pbits += bits;
    }
    const u32 T = prefix;

    u32 Cc = ROW;  // idx cutoff among keys == T
    if (e != kk) {
        u32 lo = 0, hi = ROW;
        while (hi - lo > 1u) {
            u32 mid = (lo + hi) >> 1;
            bar_lds();
            if (t == 0) sh.cnt_s = 0;
            bar_lds();
            u32 c = 0;
#pragma unroll
            for (int i = 0; i < VPT; ++i) {
#pragma unroll
                for (int j = 0; j < 4; ++j) {
                    u32 key = f2key((&v[i].x)[j]);
                    u32 idx = (u32)((i * THREADS + t) * 4 + j);
                    if (key == T && idx < mid) ++c;
                }
            }
            if (c) atomicAdd(&sh.cnt_s, c);
            bar_lds();
            if (sh.cnt_s >= kk) hi = mid; else lo = mid;
        }
        Cc = hi;
    }

#pragma unroll
    for (int i = 0; i < VPT; ++i) {
        float4 o;
#pragma unroll
        for (int j = 0; j < 4; ++j) {
            float f = (&v[i].x)[j];
            u32 key = f2key(f);
            u32 idx = (u32)((i * THREADS + t) * 4 + j);
            (&o.x)[j] = (key > T || (key == T && idx < Cc)) ? f : 0.0f;
        }
        xout[i * THREADS + t] = o;
    }
}

__global__ __launch_bounds__(THREADS, 4) void topk_stagger_kernel(
    const float* __restrict__ x, float* __restrict__ out,
    u32* __restrict__ tickets, int rpb, int nrows) {

    __shared__ Shared sh;
    const int t    = threadIdx.x;
    const int lane = t & 63;
    const int wave = t >> 6;

    // --- per-CU arrival ticket: second block on each CU staggers ~7us ---
    if (t == 0) {
        u32 hwid = 0, xcc = 0;
        asm volatile("s_getreg_b32 %0, hwreg(HW_REG_HW_ID)" : "=s"(hwid));
        asm volatile("s_getreg_b32 %0, hwreg(HW_REG_XCC_ID)" : "=s"(xcc));
        // slot = (XCC[3:0], SE/SH/CU bits HW_ID[15:8]) -> unique per CU
        u32 slot = ((xcc & 0xFu) << 8) | ((hwid >> 8) & 0xFFu);
        sh.delay = atomicAdd(&tickets[slot], 1u) & 1u;
    }
    __syncthreads();
    if (sh.delay) {
        // dependent-FMA spin: burns no memory BW, ~7us at ~2.1GHz
        float acc = 1.0f + (float)t * 1e-12f;
        for (int i = 0; i < DELAY_ITERS; ++i)
            acc = __builtin_fmaf(acc, 1.0000001f, 1e-9f);
        asm volatile("" :: "v"(acc));  // keep the chain alive
    }

    const int row0 = blockIdx.x * rpb;
    for (int r = 0; r < rpb; ++r) {
        const int row = row0 + r;
        if (row >= nrows) break;
        bar_lds();  // protect Shared reuse across rows (no vmcnt drain)
        process_row(sh, x + (size_t)row * ROW, out + (size_t)row * ROW,
                    t, lane, wave);
    }
}

extern "C" void kernel_launch(void* const* d_in, const int* in_sizes, int n_in,
                              void* d_out, int out_size, void* d_ws, size_t ws_size,
                              hipStream_t stream) {
    const float* x = (const float*)d_in[0];
    float* out = (float*)d_out;
    const int rows = in_sizes[0] / ROW;                 // 4096
    const int rpb  = (rows + NBLK - 1) / NBLK;          // 8
    // zero the per-CU ticket array (4096 slots * 4B = 16 KiB of d_ws)
    hipMemsetAsync(d_ws, 0, 4096 * sizeof(u32), stream);
    topk_stagger_kernel<<<NBLK, THREADS, 0, stream>>>(
        x, out, (u32*)d_ws, rpb, rows);
}